// Round 3
// baseline (419.058 us; speedup 1.0000x reference)
//
#include <hip/hip_runtime.h>

// Problem constants
#define S_LEN 4096
#define DMODEL 768
#define NHEAD 12
#define HDIM 64
#define DQKV 2304

typedef __attribute__((ext_vector_type(8))) __bf16 bf16x8;
typedef __attribute__((ext_vector_type(4))) float f32x4;
typedef __attribute__((ext_vector_type(8))) unsigned short ushort8;

#define LOG2E 1.4426950408889634f

static __device__ __forceinline__ unsigned short f2bf(float f) {
  unsigned int u = __float_as_uint(f);
  u += 0x7FFFu + ((u >> 16) & 1u);  // round-to-nearest-even
  return (unsigned short)(u >> 16);
}

// ---------------------------------------------------------------------------
// fp32 -> bf16 elementwise convert (n must be multiple of 8)
// ---------------------------------------------------------------------------
__global__ __launch_bounds__(256) void k_convert(const float* __restrict__ in,
                                                 unsigned short* __restrict__ out,
                                                 int n) {
  int i = (blockIdx.x * 256 + threadIdx.x) * 8;
  if (i >= n) return;
  const float4* p = reinterpret_cast<const float4*>(in + i);
  float4 a = p[0], b = p[1];
  ushort8 r;
  r[0] = f2bf(a.x); r[1] = f2bf(a.y); r[2] = f2bf(a.z); r[3] = f2bf(a.w);
  r[4] = f2bf(b.x); r[5] = f2bf(b.y); r[6] = f2bf(b.z); r[7] = f2bf(b.w);
  *reinterpret_cast<ushort8*>(out + i) = r;
}

// ---------------------------------------------------------------------------
// [K][N] fp32  ->  [N][K] bf16 transpose-convert, 64x64 tiles
// ---------------------------------------------------------------------------
__global__ __launch_bounds__(256) void k_transpose(const float* __restrict__ in,
                                                   unsigned short* __restrict__ out,
                                                   int Kdim, int Ndim) {
  __shared__ unsigned short t[64 * 65];
  int k0 = blockIdx.y * 64, n0 = blockIdx.x * 64;
  int tid = threadIdx.x;
#pragma unroll
  for (int p = 0; p < 4; ++p) {
    int r = p * 16 + (tid >> 4);   // k offset in tile
    int c = (tid & 15) * 4;        // n offset in tile
    float4 v = *reinterpret_cast<const float4*>(in + (size_t)(k0 + r) * Ndim + n0 + c);
    t[(c + 0) * 65 + r] = f2bf(v.x);
    t[(c + 1) * 65 + r] = f2bf(v.y);
    t[(c + 2) * 65 + r] = f2bf(v.z);
    t[(c + 3) * 65 + r] = f2bf(v.w);
  }
  __syncthreads();
#pragma unroll
  for (int p = 0; p < 2; ++p) {
    int task = p * 256 + tid;
    int rr = task >> 3;        // n offset
    int cc = (task & 7) * 8;   // k offset
    ushort8 r;
#pragma unroll
    for (int j = 0; j < 8; ++j) r[j] = t[rr * 65 + cc + j];
    *reinterpret_cast<ushort8*>(out + (size_t)(n0 + rr) * Kdim + k0 + cc) = r;
  }
}

// ---------------------------------------------------------------------------
// bf16 MFMA GEMM: C[M=4096][N] = A[M][768] * Bt[N][768]^T
// 128x128 block tile, BK=32, 4 waves, 4x4 16x16x32 frags per wave.
// MODE 0: QKV epilogue (scatter to Q*0.125*log2e, K, Vt[h][d][s])
// MODE 1: proj epilogue (fp32 out + bias)
// ---------------------------------------------------------------------------
template <int MODE>
__global__ __launch_bounds__(256) void k_gemm(const unsigned short* __restrict__ A,
                                              const unsigned short* __restrict__ Bt,
                                              const float* __restrict__ bias,
                                              unsigned short* __restrict__ Qb,
                                              unsigned short* __restrict__ Kb,
                                              unsigned short* __restrict__ Vt,
                                              float* __restrict__ outf) {
  constexpr int KDIM = DMODEL;       // 768
  constexpr int LDSW = 40;           // 32 + 8 pad (80B stride: 2-way bank alias = free)
  __shared__ unsigned short As[128 * LDSW];
  __shared__ unsigned short Bs[128 * LDSW];

  int tid = threadIdx.x;
  int lane = tid & 63, wave = tid >> 6;
  int wr = wave >> 1, wc = wave & 1;         // wave -> 64x64 subtile
  int m0 = blockIdx.y * 128, n0 = blockIdx.x * 128;
  int r16 = lane & 15, g = lane >> 4;

  f32x4 acc[4][4] = {};

  for (int k0 = 0; k0 < KDIM; k0 += 32) {
#pragma unroll
    for (int p = 0; p < 2; ++p) {
      int task = p * 256 + tid;
      int row = task >> 2, seg = (task & 3) * 8;
      ushort8 va = *reinterpret_cast<const ushort8*>(A + (size_t)(m0 + row) * KDIM + k0 + seg);
      *reinterpret_cast<ushort8*>(&As[row * LDSW + seg]) = va;
      ushort8 vb = *reinterpret_cast<const ushort8*>(Bt + (size_t)(n0 + row) * KDIM + k0 + seg);
      *reinterpret_cast<ushort8*>(&Bs[row * LDSW + seg]) = vb;
    }
    __syncthreads();

    bf16x8 af[4], bfr[4];
#pragma unroll
    for (int m = 0; m < 4; ++m)
      af[m] = *reinterpret_cast<const bf16x8*>(&As[(wr * 64 + m * 16 + r16) * LDSW + g * 8]);
#pragma unroll
    for (int n = 0; n < 4; ++n)
      bfr[n] = *reinterpret_cast<const bf16x8*>(&Bs[(wc * 64 + n * 16 + r16) * LDSW + g * 8]);
#pragma unroll
    for (int m = 0; m < 4; ++m)
#pragma unroll
      for (int n = 0; n < 4; ++n)
        acc[m][n] = __builtin_amdgcn_mfma_f32_16x16x32_bf16(af[m], bfr[n], acc[m][n], 0, 0, 0);
    __syncthreads();
  }

  // Epilogue. C/D frag layout: col = lane&15, row = 4*(lane>>4) + reg  [HW-verified]
#pragma unroll
  for (int m = 0; m < 4; ++m) {
    int grow0 = m0 + wr * 64 + m * 16 + 4 * g;  // s index base (4 consecutive)
#pragma unroll
    for (int n = 0; n < 4; ++n) {
      int gcol = n0 + wc * 64 + n * 16 + r16;
      float bv = bias[gcol];
      if (MODE == 0) {
        int sect = gcol / DMODEL;        // uniform per block (768 = 6*128)
        int rem = gcol - sect * DMODEL;
        int h = rem >> 6, hd = rem & 63;
        if (sect == 2) {
          // V transposed: Vt[h][hd][s]; 4 consecutive s -> one 8B store
          ushort4 pk;
          pk.x = f2bf(acc[m][n][0] + bv);
          pk.y = f2bf(acc[m][n][1] + bv);
          pk.z = f2bf(acc[m][n][2] + bv);
          pk.w = f2bf(acc[m][n][3] + bv);
          *reinterpret_cast<ushort4*>(Vt + (size_t)(h * HDIM + hd) * S_LEN + grow0) = pk;
        } else {
          unsigned short* dst = (sect == 0) ? Qb : Kb;
          // fold 1/sqrt(64) AND log2e into Q so attention works in exp2 domain
          float sc = (sect == 0) ? (0.125f * LOG2E) : 1.0f;
#pragma unroll
          for (int i = 0; i < 4; ++i)
            dst[((size_t)h * S_LEN + grow0 + i) * HDIM + hd] = f2bf((acc[m][n][i] + bv) * sc);
        }
      } else {
#pragma unroll
        for (int i = 0; i < 4; ++i)
          outf[(size_t)(grow0 + i) * DMODEL + gcol] = acc[m][n][i] + bv;
      }
    }
  }
}

// ---------------------------------------------------------------------------
// Flash attention, barrier-free, LDS-free, register-double-buffered K.
// 1D grid of 768 blocks, XCD-remapped so each XCD serves <=1.5 heads
// (K/V working set ~1.5MB -> L2-resident). 4 independent waves/block,
// each wave owns 16 q-rows; KV tiles of 64 keys, manually 2x-unrolled
// ping-pong K prefetch (named bufs, static indexing).
// Swapped QK^T with pre-permuted K row order (see R1); scores are in
// log2 domain (Q pre-scaled by 0.125*log2e). Defer-max (THR=8, T13).
// ---------------------------------------------------------------------------
__global__ __launch_bounds__(256, 3) void k_attn(const unsigned short* __restrict__ Q,
                                                 const unsigned short* __restrict__ K,
                                                 const unsigned short* __restrict__ Vt,
                                                 unsigned short* __restrict__ O) {
  int tid = threadIdx.x;
  int lane = tid & 63, wave = tid >> 6;
  int r16 = lane & 15, g = lane >> 4;

  // XCD-aware remap: blocks bid with bid&7==u form one contiguous chunk
  int bid = blockIdx.x;
  int gid = (bid & 7) * 96 + (bid >> 3);   // bijective on 0..767
  int h = gid >> 6;
  int qbase = (gid & 63) * 64 + wave * 16;

  const unsigned short* Kh = K + (size_t)h * S_LEN * HDIM;
  const unsigned short* Vh = Vt + (size_t)h * HDIM * S_LEN;

  // Q fragments (B-operand): lane holds Q[qbase+r16][8g..8g+7]
  const unsigned short* qptr = Q + ((size_t)h * S_LEN + qbase + r16) * HDIM + g * 8;
  bf16x8 qf0 = *reinterpret_cast<const bf16x8*>(qptr);
  bf16x8 qf1 = *reinterpret_cast<const bf16x8*>(qptr + 32);

  f32x4 oacc[4] = {};
  float mrow = -1e30f, lrow = 0.f;
  int rowbase = 8 * (r16 >> 2) + (r16 & 3);  // permuted K-row base for this lane

  bf16x8 ka[4][2], kb2[4][2], vbuf[4][2];

#define LOADK(KB, T)                                                                   \
  do {                                                                                 \
    const unsigned short* kbase_ = Kh + (size_t)(T) * (64 * HDIM);                     \
    _Pragma("unroll") for (int j_ = 0; j_ < 4; ++j_) {                                 \
      const unsigned short* kp_ =                                                      \
          kbase_ + (size_t)(rowbase + 32 * (j_ & 1) + 4 * (j_ >> 1)) * HDIM + g * 8;   \
      KB[j_][0] = *reinterpret_cast<const bf16x8*>(kp_);                               \
      KB[j_][1] = *reinterpret_cast<const bf16x8*>(kp_ + 32);                          \
    }                                                                                  \
  } while (0)

#define LOADV(T)                                                                       \
  do {                                                                                 \
    const unsigned short* vbase_ = Vh + (size_t)(T) * 64;                              \
    _Pragma("unroll") for (int j_ = 0; j_ < 4; ++j_) {                                 \
      const unsigned short* vp_ = vbase_ + (size_t)(j_ * 16 + r16) * S_LEN + g * 8;    \
      vbuf[j_][0] = *reinterpret_cast<const bf16x8*>(vp_);                             \
      vbuf[j_][1] = *reinterpret_cast<const bf16x8*>(vp_ + 32);                        \
    }                                                                                  \
  } while (0)

#define COMPUTE(KB)                                                                    \
  do {                                                                                 \
    f32x4 s_[4];                                                                       \
    _Pragma("unroll") for (int j_ = 0; j_ < 4; ++j_) {                                 \
      f32x4 z_ = {};                                                                   \
      z_ = __builtin_amdgcn_mfma_f32_16x16x32_bf16(KB[j_][0], qf0, z_, 0, 0, 0);       \
      s_[j_] = __builtin_amdgcn_mfma_f32_16x16x32_bf16(KB[j_][1], qf1, z_, 0, 0, 0);   \
    }                                                                                  \
    float pmax_ = fmaxf(fmaxf(fmaxf(s_[0][0], s_[0][1]), fmaxf(s_[0][2], s_[0][3])),   \
                        fmaxf(fmaxf(s_[1][0], s_[1][1]), fmaxf(s_[1][2], s_[1][3])));  \
    float pm2_ = fmaxf(fmaxf(fmaxf(s_[2][0], s_[2][1]), fmaxf(s_[2][2], s_[2][3])),    \
                       fmaxf(fmaxf(s_[3][0], s_[3][1]), fmaxf(s_[3][2], s_[3][3])));   \
    pmax_ = fmaxf(pmax_, pm2_);                                                        \
    pmax_ = fmaxf(pmax_, __shfl_xor(pmax_, 16));                                       \
    pmax_ = fmaxf(pmax_, __shfl_xor(pmax_, 32));                                       \
    if (__any(pmax_ > mrow + 8.f)) {                                                   \
      float mnew_ = fmaxf(mrow, pmax_);                                                \
      float al_ = exp2f(mrow - mnew_);                                                 \
      float a0_ = __shfl(al_, 20 * g + 0), a1_ = __shfl(al_, 20 * g + 1);              \
      float a2_ = __shfl(al_, 20 * g + 2), a3_ = __shfl(al_, 20 * g + 3);              \
      _Pragma("unroll") for (int j_ = 0; j_ < 4; ++j_) {                               \
        oacc[j_][0] *= a0_; oacc[j_][1] *= a1_;                                        \
        oacc[j_][2] *= a2_; oacc[j_][3] *= a3_;                                        \
      }                                                                                \
      lrow *= al_;                                                                     \
      mrow = mnew_;                                                                    \
    }                                                                                  \
    float p_[4][4];                                                                    \
    float rs_ = 0.f;                                                                   \
    _Pragma("unroll") for (int j_ = 0; j_ < 4; ++j_) {                                 \
      _Pragma("unroll") for (int i_ = 0; i_ < 4; ++i_) {                               \
        float e_ = exp2f(s_[j_][i_] - mrow);                                           \
        p_[j_][i_] = e_;                                                               \
        rs_ += e_;                                                                     \
      }                                                                                \
    }                                                                                  \
    rs_ += __shfl_xor(rs_, 16);                                                        \
    rs_ += __shfl_xor(rs_, 32);                                                        \
    lrow += rs_;                                                                       \
    ushort8 u0_, u1_;                                                                  \
    _Pragma("unroll") for (int e_ = 0; e_ < 8; ++e_) {                                 \
      u0_[e_] = f2bf(p_[2 * (e_ >> 2)][e_ & 3]);                                       \
      u1_[e_] = f2bf(p_[1 + 2 * (e_ >> 2)][e_ & 3]);                                   \
    }                                                                                  \
    bf16x8 pa0_ = __builtin_bit_cast(bf16x8, u0_);                                     \
    bf16x8 pa1_ = __builtin_bit_cast(bf16x8, u1_);                                     \
    _Pragma("unroll") for (int j_ = 0; j_ < 4; ++j_) {                                 \
      oacc[j_] = __builtin_amdgcn_mfma_f32_16x16x32_bf16(pa0_, vbuf[j_][0], oacc[j_], 0, 0, 0); \
      oacc[j_] = __builtin_amdgcn_mfma_f32_16x16x32_bf16(pa1_, vbuf[j_][1], oacc[j_], 0, 0, 0); \
    }                                                                                  \
  } while (0)

  LOADK(ka, 0);
  for (int t = 0; t < 64; t += 2) {
    // half 1: compute tile t with ka; prefetch K(t+1) -> kb2
    LOADV(t);
    LOADK(kb2, t + 1);
    COMPUTE(ka);
    // half 2: compute tile t+1 with kb2; prefetch K(t+2) -> ka
    LOADV(t + 1);
    int t2 = (t + 2 < 64) ? (t + 2) : 63;
    LOADK(ka, t2);
    COMPUTE(kb2);
  }
#undef LOADK
#undef LOADV
#undef COMPUTE

  // ---- epilogue: O[s][h*64+d] bf16, rows q = 4g+i need 1/l from lane 4g+i
#pragma unroll
  for (int i = 0; i < 4; ++i) {
    float linv = 1.0f / __shfl(lrow, 20 * g + i);
    int srow = qbase + 4 * g + i;
#pragma unroll
    for (int j = 0; j < 4; ++j) {
      int col = h * HDIM + j * 16 + r16;
      O[(size_t)srow * DMODEL + col] = f2bf(oacc[j][i] * linv);
    }
  }
}

// ---------------------------------------------------------------------------
extern "C" void kernel_launch(void* const* d_in, const int* in_sizes, int n_in,
                              void* d_out, int out_size, void* d_ws, size_t ws_size,
                              hipStream_t stream) {
  const float* x = (const float*)d_in[0];       // [4096][768]
  const float* w_qkv = (const float*)d_in[1];   // [768][2304]
  const float* b_qkv = (const float*)d_in[2];   // [2304]
  const float* w_proj = (const float*)d_in[3];  // [768][768]
  const float* b_proj = (const float*)d_in[4];  // [768]
  float* out = (float*)d_out;                   // [4096][768]

  unsigned short* ws16 = (unsigned short*)d_ws;
  unsigned short* xb = ws16;                                   // 4096*768
  unsigned short* wqkvT = xb + (size_t)S_LEN * DMODEL;         // 2304*768
  unsigned short* wprojT = wqkvT + (size_t)DQKV * DMODEL;      // 768*768
  unsigned short* Qb = wprojT + (size_t)DMODEL * DMODEL;       // 12*4096*64
  unsigned short* Kb = Qb + (size_t)NHEAD * S_LEN * HDIM;
  unsigned short* Vt = Kb + (size_t)NHEAD * S_LEN * HDIM;
  unsigned short* Ob = xb;  // alias: x dead after QKV GEMM

  // 1) convert x
  k_convert<<<(S_LEN * DMODEL) / (256 * 8), 256, 0, stream>>>(x, xb, S_LEN * DMODEL);
  // 2) transpose-convert weights to [N][K] bf16
  k_transpose<<<dim3(DQKV / 64, DMODEL / 64), 256, 0, stream>>>(w_qkv, wqkvT, DMODEL, DQKV);
  k_transpose<<<dim3(DMODEL / 64, DMODEL / 64), 256, 0, stream>>>(w_proj, wprojT, DMODEL, DMODEL);
  // 3) QKV GEMM + scatter
  k_gemm<0><<<dim3(DQKV / 128, S_LEN / 128), 256, 0, stream>>>(xb, wqkvT, b_qkv, Qb, Kb, Vt, nullptr);
  // 4) attention (1D grid, XCD-remapped in-kernel)
  k_attn<<<768, 256, 0, stream>>>(Qb, Kb, Vt, Ob);
  // 5) output projection
  k_gemm<1><<<dim3(DMODEL / 128, S_LEN / 128), 256, 0, stream>>>(Ob, wprojT, b_proj, nullptr, nullptr, nullptr, out);
}

// Round 4
// 211.120 us; speedup vs baseline: 1.9849x; 1.9849x over previous
//
#include <hip/hip_runtime.h>

// Problem constants
#define S_LEN 4096
#define DMODEL 768
#define NHEAD 12
#define HDIM 64
#define DQKV 2304

typedef __attribute__((ext_vector_type(8))) __bf16 bf16x8;
typedef __attribute__((ext_vector_type(4))) float f32x4;
typedef __attribute__((ext_vector_type(8))) unsigned short ushort8;

#define LOG2E 1.4426950408889634f

static __device__ __forceinline__ unsigned short f2bf(float f) {
  unsigned int u = __float_as_uint(f);
  u += 0x7FFFu + ((u >> 16) & 1u);  // round-to-nearest-even
  return (unsigned short)(u >> 16);
}

// async global -> LDS, 16B per lane. Dest must be wave-uniform; HW writes
// lptr + lane*16. Global src is per-lane (contiguous here -> coalesced).
static __device__ __forceinline__ void gload_lds16(const unsigned short* g, unsigned short* l) {
  __builtin_amdgcn_global_load_lds(
      (const __attribute__((address_space(1))) unsigned int*)g,
      (__attribute__((address_space(3))) unsigned int*)l, 16, 0, 0);
}

// ---------------------------------------------------------------------------
// fp32 -> bf16 elementwise convert (n must be multiple of 8)
// ---------------------------------------------------------------------------
__global__ __launch_bounds__(256) void k_convert(const float* __restrict__ in,
                                                 unsigned short* __restrict__ out,
                                                 int n) {
  int i = (blockIdx.x * 256 + threadIdx.x) * 8;
  if (i >= n) return;
  const float4* p = reinterpret_cast<const float4*>(in + i);
  float4 a = p[0], b = p[1];
  ushort8 r;
  r[0] = f2bf(a.x); r[1] = f2bf(a.y); r[2] = f2bf(a.z); r[3] = f2bf(a.w);
  r[4] = f2bf(b.x); r[5] = f2bf(b.y); r[6] = f2bf(b.z); r[7] = f2bf(b.w);
  *reinterpret_cast<ushort8*>(out + i) = r;
}

// ---------------------------------------------------------------------------
// [K][N] fp32  ->  [N][K] bf16 transpose-convert, 64x64 tiles
// ---------------------------------------------------------------------------
__global__ __launch_bounds__(256) void k_transpose(const float* __restrict__ in,
                                                   unsigned short* __restrict__ out,
                                                   int Kdim, int Ndim) {
  __shared__ unsigned short t[64 * 65];
  int k0 = blockIdx.y * 64, n0 = blockIdx.x * 64;
  int tid = threadIdx.x;
#pragma unroll
  for (int p = 0; p < 4; ++p) {
    int r = p * 16 + (tid >> 4);   // k offset in tile
    int c = (tid & 15) * 4;        // n offset in tile
    float4 v = *reinterpret_cast<const float4*>(in + (size_t)(k0 + r) * Ndim + n0 + c);
    t[(c + 0) * 65 + r] = f2bf(v.x);
    t[(c + 1) * 65 + r] = f2bf(v.y);
    t[(c + 2) * 65 + r] = f2bf(v.z);
    t[(c + 3) * 65 + r] = f2bf(v.w);
  }
  __syncthreads();
#pragma unroll
  for (int p = 0; p < 2; ++p) {
    int task = p * 256 + tid;
    int rr = task >> 3;        // n offset
    int cc = (task & 7) * 8;   // k offset
    ushort8 r;
#pragma unroll
    for (int j = 0; j < 8; ++j) r[j] = t[rr * 65 + cc + j];
    *reinterpret_cast<ushort8*>(out + (size_t)(n0 + rr) * Kdim + k0 + cc) = r;
  }
}

// ---------------------------------------------------------------------------
// bf16 MFMA GEMM: C[M=4096][N] = A[M][768] * Bt[N][768]^T
// 128x128 block tile, BK=32, 4 waves, 4x4 16x16x32 frags per wave.
// MODE 0: QKV epilogue. Q -> [h][s][d] scaled by 0.125*log2e.
//         K,V -> FRAGMENT-LINEAR layouts (see k_attn): per head, per 64-key
//         tile, 8 frags x 64 lanes x 8 elems laid out so a wave-load of the
//         fragment is 1KB contiguous.
// MODE 1: proj epilogue (fp32 out + bias)
// ---------------------------------------------------------------------------
template <int MODE>
__global__ __launch_bounds__(256) void k_gemm(const unsigned short* __restrict__ A,
                                              const unsigned short* __restrict__ Bt,
                                              const float* __restrict__ bias,
                                              unsigned short* __restrict__ Qb,
                                              unsigned short* __restrict__ Kf,
                                              unsigned short* __restrict__ Vf,
                                              float* __restrict__ outf) {
  constexpr int KDIM = DMODEL;       // 768
  constexpr int LDSW = 40;           // 32 + 8 pad (80B stride: 2-way bank alias = free)
  __shared__ unsigned short As[128 * LDSW];
  __shared__ unsigned short Bs[128 * LDSW];

  int tid = threadIdx.x;
  int lane = tid & 63, wave = tid >> 6;
  int wr = wave >> 1, wc = wave & 1;         // wave -> 64x64 subtile
  int m0 = blockIdx.y * 128, n0 = blockIdx.x * 128;
  int r16 = lane & 15, g = lane >> 4;

  f32x4 acc[4][4] = {};

  for (int k0 = 0; k0 < KDIM; k0 += 32) {
#pragma unroll
    for (int p = 0; p < 2; ++p) {
      int task = p * 256 + tid;
      int row = task >> 2, seg = (task & 3) * 8;
      ushort8 va = *reinterpret_cast<const ushort8*>(A + (size_t)(m0 + row) * KDIM + k0 + seg);
      *reinterpret_cast<ushort8*>(&As[row * LDSW + seg]) = va;
      ushort8 vb = *reinterpret_cast<const ushort8*>(Bt + (size_t)(n0 + row) * KDIM + k0 + seg);
      *reinterpret_cast<ushort8*>(&Bs[row * LDSW + seg]) = vb;
    }
    __syncthreads();

    bf16x8 af[4], bfr[4];
#pragma unroll
    for (int m = 0; m < 4; ++m)
      af[m] = *reinterpret_cast<const bf16x8*>(&As[(wr * 64 + m * 16 + r16) * LDSW + g * 8]);
#pragma unroll
    for (int n = 0; n < 4; ++n)
      bfr[n] = *reinterpret_cast<const bf16x8*>(&Bs[(wc * 64 + n * 16 + r16) * LDSW + g * 8]);
#pragma unroll
    for (int m = 0; m < 4; ++m)
#pragma unroll
      for (int n = 0; n < 4; ++n)
        acc[m][n] = __builtin_amdgcn_mfma_f32_16x16x32_bf16(af[m], bfr[n], acc[m][n], 0, 0, 0);
    __syncthreads();
  }

  // Epilogue. C/D frag layout: col = lane&15, row = 4*(lane>>4) + reg  [HW-verified]
#pragma unroll
  for (int m = 0; m < 4; ++m) {
    int grow0 = m0 + wr * 64 + m * 16 + 4 * g;  // s index base (4 consecutive)
#pragma unroll
    for (int n = 0; n < 4; ++n) {
      int gcol = n0 + wc * 64 + n * 16 + r16;
      float bv = bias[gcol];
      if (MODE == 0) {
        int sect = gcol / DMODEL;        // uniform per block (768 = 6*128)
        int rem = gcol - sect * DMODEL;
        int h = rem >> 6, hd = rem & 63;
        if (sect == 2) {
          // V fragment-linear: elem (h,tile,f=j*2+kk,lane2=g2*16+r16v,e)
          //   = V[d = j*16+r16v][s = tile*64 + kk*32 + g2*8 + e]
          int j = hd >> 4, r16v = hd & 15;
          int tile = grow0 >> 6, kk = (grow0 >> 5) & 1, g2 = (grow0 >> 3) & 3, e0 = grow0 & 7;
          size_t base = (((size_t)h * 64 + tile) * 8 + (j * 2 + kk)) * 512 +
                        (size_t)(g2 * 16 + r16v) * 8 + e0;
          ushort4 pk;
          pk.x = f2bf(acc[m][n][0] + bv);
          pk.y = f2bf(acc[m][n][1] + bv);
          pk.z = f2bf(acc[m][n][2] + bv);
          pk.w = f2bf(acc[m][n][3] + bv);
          *reinterpret_cast<ushort4*>(Vf + base) = pk;
        } else if (sect == 0) {
          // Q: [h][s][d], folded 1/sqrt(64)*log2e (attention runs in exp2 domain)
#pragma unroll
          for (int i = 0; i < 4; ++i)
            Qb[((size_t)h * S_LEN + grow0 + i) * HDIM + hd] =
                f2bf((acc[m][n][i] + bv) * (0.125f * LOG2E));
        } else {
          // K fragment-linear: elem (h,tile,f=j*2+kk,lane2=g2*16+r16l,e)
          //   = K[s = tile*64 + krow][d = kk*32 + g2*8 + e]
          // krow = 32*(j&1) + 4*(j>>1) + 8*(r16l>>2) + (r16l&3)
          int kk = hd >> 5, g2 = (hd >> 3) & 3, e = hd & 7;
#pragma unroll
          for (int i = 0; i < 4; ++i) {
            int s = grow0 + i;
            int tile = s >> 6, r = s & 63;
            int j = (((r >> 2) & 1) << 1) | (r >> 5);
            int r16l = (r & 3) | (((r >> 3) & 3) << 2);
            size_t idx = (((size_t)h * 64 + tile) * 8 + (j * 2 + kk)) * 512 +
                         (size_t)(g2 * 16 + r16l) * 8 + e;
            Kf[idx] = f2bf(acc[m][n][i] + bv);
          }
        }
      } else {
#pragma unroll
        for (int i = 0; i < 4; ++i)
          outf[(size_t)(grow0 + i) * DMODEL + gcol] = acc[m][n][i] + bv;
      }
    }
  }
}

// ---------------------------------------------------------------------------
// Flash attention with LDS-staged, fragment-linear K/V.
// 1D grid of 768 blocks, XCD-remapped (each XCD serves <=1.5 heads -> K/V
// L2-resident). 4 waves/block, each wave owns 16 q-rows; all waves share the
// same K/V tile staged once per block via global_load_lds (coalesced 1KB
// chunks), double-buffered, m97-style 2-barrier loop.
// Swapped QK^T (scores in exp2 domain), lane-local P repack, defer-max.
// ---------------------------------------------------------------------------
__global__ __launch_bounds__(256, 3) void k_attn(const unsigned short* __restrict__ Q,
                                                 const unsigned short* __restrict__ Kf,
                                                 const unsigned short* __restrict__ Vf,
                                                 unsigned short* __restrict__ O) {
  __shared__ unsigned short ldsK[2][4096];
  __shared__ unsigned short ldsV[2][4096];

  int tid = threadIdx.x;
  int lane = tid & 63, wave = tid >> 6;
  int r16 = lane & 15, g = lane >> 4;

  // XCD-aware remap (bijective on 0..767)
  int bid = blockIdx.x;
  int gid = (bid & 7) * 96 + (bid >> 3);
  int h = gid >> 6;
  int qbase = (gid & 63) * 64 + wave * 16;

  const unsigned short* KfH = Kf + (size_t)h * (64 * 4096);
  const unsigned short* VfH = Vf + (size_t)h * (64 * 4096);

  // Q fragments (B-operand): lane holds Q[qbase+r16][8g..8g+7]
  const unsigned short* qptr = Q + ((size_t)h * S_LEN + qbase + r16) * HDIM + g * 8;
  bf16x8 qf0 = *reinterpret_cast<const bf16x8*>(qptr);
  bf16x8 qf1 = *reinterpret_cast<const bf16x8*>(qptr + 32);

  f32x4 oacc[4] = {};
  float mrow = -1e30f, lrow = 0.f;

  int c0 = wave, c1 = wave + 4;  // this wave's two 1KB chunks per buffer

#define STAGE(BUF, T)                                                        \
  do {                                                                       \
    const unsigned short* kg_ = KfH + (size_t)(T) * 4096;                    \
    const unsigned short* vg_ = VfH + (size_t)(T) * 4096;                    \
    gload_lds16(kg_ + c0 * 512 + lane * 8, &ldsK[BUF][c0 * 512]);            \
    gload_lds16(kg_ + c1 * 512 + lane * 8, &ldsK[BUF][c1 * 512]);            \
    gload_lds16(vg_ + c0 * 512 + lane * 8, &ldsV[BUF][c0 * 512]);            \
    gload_lds16(vg_ + c1 * 512 + lane * 8, &ldsV[BUF][c1 * 512]);            \
  } while (0)

  STAGE(0, 0);
  for (int t = 0; t < 64; ++t) {
    int cur = t & 1;
    if (t < 63) STAGE(cur ^ 1, t + 1);
    __syncthreads();  // drains vmcnt -> buf[cur] (and prefetch) complete

    // ---- fragments from LDS (lane-contiguous b128, conflict-free)
    bf16x8 kfr[8], vfr[8];
#pragma unroll
    for (int f = 0; f < 8; ++f) {
      kfr[f] = *reinterpret_cast<const bf16x8*>(&ldsK[cur][f * 512 + lane * 8]);
      vfr[f] = *reinterpret_cast<const bf16x8*>(&ldsV[cur][f * 512 + lane * 8]);
    }

    // ---- QK^T (swapped): s[j] = P_raw[q=r16][keys of frag j], exp2 domain
    f32x4 s[4];
#pragma unroll
    for (int j = 0; j < 4; ++j) {
      f32x4 z = {};
      z = __builtin_amdgcn_mfma_f32_16x16x32_bf16(kfr[2 * j], qf0, z, 0, 0, 0);
      s[j] = __builtin_amdgcn_mfma_f32_16x16x32_bf16(kfr[2 * j + 1], qf1, z, 0, 0, 0);
    }

    // ---- online softmax (per-lane q=r16), defer-max THR=8
    float pmax = fmaxf(fmaxf(fmaxf(s[0][0], s[0][1]), fmaxf(s[0][2], s[0][3])),
                       fmaxf(fmaxf(s[1][0], s[1][1]), fmaxf(s[1][2], s[1][3])));
    float pm2 = fmaxf(fmaxf(fmaxf(s[2][0], s[2][1]), fmaxf(s[2][2], s[2][3])),
                      fmaxf(fmaxf(s[3][0], s[3][1]), fmaxf(s[3][2], s[3][3])));
    pmax = fmaxf(pmax, pm2);
    pmax = fmaxf(pmax, __shfl_xor(pmax, 16));
    pmax = fmaxf(pmax, __shfl_xor(pmax, 32));
    if (__any(pmax > mrow + 8.f)) {
      float mnew = fmaxf(mrow, pmax);
      float al = exp2f(mrow - mnew);
      float a0 = __shfl(al, 20 * g + 0), a1 = __shfl(al, 20 * g + 1);
      float a2 = __shfl(al, 20 * g + 2), a3 = __shfl(al, 20 * g + 3);
#pragma unroll
      for (int j = 0; j < 4; ++j) {
        oacc[j][0] *= a0; oacc[j][1] *= a1;
        oacc[j][2] *= a2; oacc[j][3] *= a3;
      }
      lrow *= al;
      mrow = mnew;
    }
    float p[4][4];
    float rs = 0.f;
#pragma unroll
    for (int j = 0; j < 4; ++j)
#pragma unroll
      for (int i = 0; i < 4; ++i) {
        float e = exp2f(s[j][i] - mrow);
        p[j][i] = e;
        rs += e;
      }
    rs += __shfl_xor(rs, 16);
    rs += __shfl_xor(rs, 32);
    lrow += rs;

    // ---- lane-local P -> bf16 A-fragments: pa[kk][e] = p[kk + 2*(e>>2)][e&3]
    ushort8 u0, u1;
#pragma unroll
    for (int e = 0; e < 8; ++e) {
      u0[e] = f2bf(p[2 * (e >> 2)][e & 3]);
      u1[e] = f2bf(p[1 + 2 * (e >> 2)][e & 3]);
    }
    bf16x8 pa0 = __builtin_bit_cast(bf16x8, u0);
    bf16x8 pa1 = __builtin_bit_cast(bf16x8, u1);

    // ---- PV
#pragma unroll
    for (int j = 0; j < 4; ++j) {
      oacc[j] = __builtin_amdgcn_mfma_f32_16x16x32_bf16(pa0, vfr[2 * j], oacc[j], 0, 0, 0);
      oacc[j] = __builtin_amdgcn_mfma_f32_16x16x32_bf16(pa1, vfr[2 * j + 1], oacc[j], 0, 0, 0);
    }
    __syncthreads();  // all waves done with buf[cur] before next stage overwrites
  }
#undef STAGE

  // ---- epilogue: O[s][h*64+d] bf16, rows q = 4g+i need 1/l from lane 4g+i
#pragma unroll
  for (int i = 0; i < 4; ++i) {
    float linv = 1.0f / __shfl(lrow, 20 * g + i);
    int srow = qbase + 4 * g + i;
#pragma unroll
    for (int j = 0; j < 4; ++j) {
      int col = h * HDIM + j * 16 + r16;
      O[(size_t)srow * DMODEL + col] = f2bf(oacc[j][i] * linv);
    }
  }
}

// ---------------------------------------------------------------------------
extern "C" void kernel_launch(void* const* d_in, const int* in_sizes, int n_in,
                              void* d_out, int out_size, void* d_ws, size_t ws_size,
                              hipStream_t stream) {
  const float* x = (const float*)d_in[0];       // [4096][768]
  const float* w_qkv = (const float*)d_in[1];   // [768][2304]
  const float* b_qkv = (const float*)d_in[2];   // [2304]
  const float* w_proj = (const float*)d_in[3];  // [768][768]
  const float* b_proj = (const float*)d_in[4];  // [768]
  float* out = (float*)d_out;                   // [4096][768]

  unsigned short* ws16 = (unsigned short*)d_ws;
  unsigned short* xb = ws16;                                   // 4096*768
  unsigned short* wqkvT = xb + (size_t)S_LEN * DMODEL;         // 2304*768
  unsigned short* wprojT = wqkvT + (size_t)DQKV * DMODEL;      // 768*768
  unsigned short* Qb = wprojT + (size_t)DMODEL * DMODEL;       // 12*4096*64
  unsigned short* Kf = Qb + (size_t)NHEAD * S_LEN * HDIM;
  unsigned short* Vf = Kf + (size_t)NHEAD * S_LEN * HDIM;
  unsigned short* Ob = xb;  // alias: x dead after QKV GEMM

  // 1) convert x
  k_convert<<<(S_LEN * DMODEL) / (256 * 8), 256, 0, stream>>>(x, xb, S_LEN * DMODEL);
  // 2) transpose-convert weights to [N][K] bf16
  k_transpose<<<dim3(DQKV / 64, DMODEL / 64), 256, 0, stream>>>(w_qkv, wqkvT, DMODEL, DQKV);
  k_transpose<<<dim3(DMODEL / 64, DMODEL / 64), 256, 0, stream>>>(w_proj, wprojT, DMODEL, DMODEL);
  // 3) QKV GEMM + fragment-linear scatter
  k_gemm<0><<<dim3(DQKV / 128, S_LEN / 128), 256, 0, stream>>>(xb, wqkvT, b_qkv, Qb, Kf, Vf, nullptr);
  // 4) attention (1D grid, XCD-remapped in-kernel)
  k_attn<<<768, 256, 0, stream>>>(Qb, Kf, Vf, Ob);
  // 5) output projection
  k_gemm<1><<<dim3(DMODEL / 128, S_LEN / 128), 256, 0, stream>>>(Ob, wprojT, b_proj, nullptr, nullptr, nullptr, out);
}

// Round 6
// 160.947 us; speedup vs baseline: 2.6037x; 1.3117x over previous
//
#include <hip/hip_runtime.h>

// Problem constants
#define S_LEN 4096
#define DMODEL 768
#define NHEAD 12
#define HDIM 64
#define DQKV 2304

typedef __attribute__((ext_vector_type(8))) __bf16 bf16x8;
typedef __attribute__((ext_vector_type(4))) float f32x4;
typedef __attribute__((ext_vector_type(8))) unsigned short ushort8;

#define LOG2E 1.4426950408889634f

static __device__ __forceinline__ unsigned short f2bf(float f) {
  unsigned int u = __float_as_uint(f);
  u += 0x7FFFu + ((u >> 16) & 1u);  // round-to-nearest-even
  return (unsigned short)(u >> 16);
}

// async global -> LDS, 16B per lane. Dest must be wave-uniform; HW writes
// lptr + lane*16. Global src is per-lane (contiguous here -> coalesced).
static __device__ __forceinline__ void gload_lds16(const unsigned short* g, unsigned short* l) {
  __builtin_amdgcn_global_load_lds(
      (const __attribute__((address_space(1))) unsigned int*)g,
      (__attribute__((address_space(3))) unsigned int*)l, 16, 0, 0);
}

// ---------------------------------------------------------------------------
// fp32 -> bf16 elementwise convert (n must be multiple of 8)
// ---------------------------------------------------------------------------
__global__ __launch_bounds__(256) void k_convert(const float* __restrict__ in,
                                                 unsigned short* __restrict__ out,
                                                 int n) {
  int i = (blockIdx.x * 256 + threadIdx.x) * 8;
  if (i >= n) return;
  const float4* p = reinterpret_cast<const float4*>(in + i);
  float4 a = p[0], b = p[1];
  ushort8 r;
  r[0] = f2bf(a.x); r[1] = f2bf(a.y); r[2] = f2bf(a.z); r[3] = f2bf(a.w);
  r[4] = f2bf(b.x); r[5] = f2bf(b.y); r[6] = f2bf(b.z); r[7] = f2bf(b.w);
  *reinterpret_cast<ushort8*>(out + i) = r;
}

// ---------------------------------------------------------------------------
// [K][N] fp32  ->  [N][K] bf16 transpose-convert, 64x64 tiles
// ---------------------------------------------------------------------------
__global__ __launch_bounds__(256) void k_transpose(const float* __restrict__ in,
                                                   unsigned short* __restrict__ out,
                                                   int Kdim, int Ndim) {
  __shared__ unsigned short t[64 * 65];
  int k0 = blockIdx.y * 64, n0 = blockIdx.x * 64;
  int tid = threadIdx.x;
#pragma unroll
  for (int p = 0; p < 4; ++p) {
    int r = p * 16 + (tid >> 4);   // k offset in tile
    int c = (tid & 15) * 4;        // n offset in tile
    float4 v = *reinterpret_cast<const float4*>(in + (size_t)(k0 + r) * Ndim + n0 + c);
    t[(c + 0) * 65 + r] = f2bf(v.x);
    t[(c + 1) * 65 + r] = f2bf(v.y);
    t[(c + 2) * 65 + r] = f2bf(v.z);
    t[(c + 3) * 65 + r] = f2bf(v.w);
  }
  __syncthreads();
#pragma unroll
  for (int p = 0; p < 2; ++p) {
    int task = p * 256 + tid;
    int rr = task >> 3;        // n offset
    int cc = (task & 7) * 8;   // k offset
    ushort8 r;
#pragma unroll
    for (int j = 0; j < 8; ++j) r[j] = t[rr * 65 + cc + j];
    *reinterpret_cast<ushort8*>(out + (size_t)(n0 + rr) * Kdim + k0 + cc) = r;
  }
}

// ---------------------------------------------------------------------------
// bf16 MFMA GEMM: C[M=4096][N] = A[M][768] * Bt[N][768]^T
// 128x128 block tile, BK=32, 4 waves, 4x4 16x16x32 frags per wave.
// global_load_lds staging (16B, linear LDS), double-buffered, ONE barrier
// per K-step (stage-after-read order; stage drains at next barrier).
// MODE 0: QKV epilogue (Q scaled, K/V fragment-linear scatter)
// MODE 1: proj epilogue (fp32 out + bias)
// ---------------------------------------------------------------------------
template <int MODE>
__global__ __launch_bounds__(256) void k_gemm(const unsigned short* __restrict__ A,
                                              const unsigned short* __restrict__ Bt,
                                              const float* __restrict__ bias,
                                              unsigned short* __restrict__ Qb,
                                              unsigned short* __restrict__ Kf,
                                              unsigned short* __restrict__ Vf,
                                              float* __restrict__ outf) {
  __shared__ unsigned short As[2][128 * 32];
  __shared__ unsigned short Bs[2][128 * 32];

  int tid = threadIdx.x;
  int lane = tid & 63, wave = tid >> 6;
  int wr = wave >> 1, wc = wave & 1;         // wave -> 64x64 subtile
  int m0 = blockIdx.y * 128, n0 = blockIdx.x * 128;
  int r16 = lane & 15, g = lane >> 4;

  // staging: 8 chunks of 1KB per tile (16 rows x 64B); wave stages 2 of A + 2 of B
  int ca0 = wave * 2, ca1 = wave * 2 + 1;
  int srow = lane >> 2, scol = (lane & 3) * 8;  // within-chunk source (row, col elems)

  f32x4 acc[4][4] = {};

#define GSTAGE(BUF, K0)                                                                 \
  do {                                                                                  \
    gload_lds16(A + (size_t)(m0 + ca0 * 16 + srow) * DMODEL + (K0) + scol,              \
                &As[BUF][ca0 * 512]);                                                   \
    gload_lds16(A + (size_t)(m0 + ca1 * 16 + srow) * DMODEL + (K0) + scol,              \
                &As[BUF][ca1 * 512]);                                                   \
    gload_lds16(Bt + (size_t)(n0 + ca0 * 16 + srow) * DMODEL + (K0) + scol,             \
                &Bs[BUF][ca0 * 512]);                                                   \
    gload_lds16(Bt + (size_t)(n0 + ca1 * 16 + srow) * DMODEL + (K0) + scol,             \
                &Bs[BUF][ca1 * 512]);                                                   \
  } while (0)

  GSTAGE(0, 0);
  for (int kt = 0; kt < DMODEL / 32; ++kt) {
    int cur = kt & 1;
    __syncthreads();  // drains prev stage (own vmcnt) + all waves' reads of buf[cur^1]

    bf16x8 af[4], bfr[4];
#pragma unroll
    for (int m = 0; m < 4; ++m)
      af[m] = *reinterpret_cast<const bf16x8*>(&As[cur][(wr * 64 + m * 16 + r16) * 32 + g * 8]);
#pragma unroll
    for (int n = 0; n < 4; ++n)
      bfr[n] = *reinterpret_cast<const bf16x8*>(&Bs[cur][(wc * 64 + n * 16 + r16) * 32 + g * 8]);

    if (kt < DMODEL / 32 - 1) GSTAGE(cur ^ 1, (kt + 1) * 32);

#pragma unroll
    for (int m = 0; m < 4; ++m)
#pragma unroll
      for (int n = 0; n < 4; ++n)
        acc[m][n] = __builtin_amdgcn_mfma_f32_16x16x32_bf16(af[m], bfr[n], acc[m][n], 0, 0, 0);
  }
#undef GSTAGE

  // Epilogue. C/D frag layout: col = lane&15, row = 4*(lane>>4) + reg  [HW-verified]
#pragma unroll
  for (int m = 0; m < 4; ++m) {
    int grow0 = m0 + wr * 64 + m * 16 + 4 * g;  // s index base (4 consecutive)
#pragma unroll
    for (int n = 0; n < 4; ++n) {
      int gcol = n0 + wc * 64 + n * 16 + r16;
      float bv = bias[gcol];
      if (MODE == 0) {
        int sect = gcol / DMODEL;        // uniform per block (768 = 6*128)
        int rem = gcol - sect * DMODEL;
        int h = rem >> 6, hd = rem & 63;
        if (sect == 2) {
          // V fragment-linear: elem (h,tile,f=j*2+kk,lane2=g2*16+r16v,e)
          //   = V[d = j*16+r16v][s = tile*64 + kk*32 + g2*8 + e]
          int j = hd >> 4, r16v = hd & 15;
          int tile = grow0 >> 6, kk = (grow0 >> 5) & 1, g2 = (grow0 >> 3) & 3, e0 = grow0 & 7;
          size_t base = (((size_t)h * 64 + tile) * 8 + (j * 2 + kk)) * 512 +
                        (size_t)(g2 * 16 + r16v) * 8 + e0;
          ushort4 pk;
          pk.x = f2bf(acc[m][n][0] + bv);
          pk.y = f2bf(acc[m][n][1] + bv);
          pk.z = f2bf(acc[m][n][2] + bv);
          pk.w = f2bf(acc[m][n][3] + bv);
          *reinterpret_cast<ushort4*>(Vf + base) = pk;
        } else if (sect == 0) {
          // Q: [h][s][d], folded 1/sqrt(64)*log2e (attention runs in exp2 domain)
#pragma unroll
          for (int i = 0; i < 4; ++i)
            Qb[((size_t)h * S_LEN + grow0 + i) * HDIM + hd] =
                f2bf((acc[m][n][i] + bv) * (0.125f * LOG2E));
        } else {
          // K fragment-linear: elem (h,tile,f=j*2+kk,lane2=g2*16+r16l,e)
          //   = K[s = tile*64 + krow][d = kk*32 + g2*8 + e]
          // krow = 32*(j&1) + 4*(j>>1) + 8*(r16l>>2) + (r16l&3)
          int kk = hd >> 5, g2 = (hd >> 3) & 3, e = hd & 7;
#pragma unroll
          for (int i = 0; i < 4; ++i) {
            int s = grow0 + i;
            int tile = s >> 6, r = s & 63;
            int j = (((r >> 2) & 1) << 1) | (r >> 5);
            int r16l = (r & 3) | (((r >> 3) & 3) << 2);
            size_t idx = (((size_t)h * 64 + tile) * 8 + (j * 2 + kk)) * 512 +
                         (size_t)(g2 * 16 + r16l) * 8 + e;
            Kf[idx] = f2bf(acc[m][n][i] + bv);
          }
        }
      } else {
#pragma unroll
        for (int i = 0; i < 4; ++i)
          outf[(size_t)(grow0 + i) * DMODEL + gcol] = acc[m][n][i] + bv;
      }
    }
  }
}

// ---------------------------------------------------------------------------
// Flash attention, LDS-staged fragment-linear K/V, defer-max online softmax.
// Scores in exp2 domain (Q pre-scaled by 0.125*log2e). Defer-max THR=8:
// rescale O/l only when a tile's row-max exceeds running max by >8 (rare;
// __any-gated wave-uniform branch). p = exp2(s - mrow) <= 2^8, which bf16
// handles (proven 1.2e-3 in R4); WITHOUT max subtraction the dominant p's
// 2^-9 rounding doesn't cancel and absmax blows to 1.6e-2 (R5 fail).
// Per-lane partial l (rescaled by alpha on max updates), ONE cross-lane
// reduce at the end. Double-buffered, ONE __syncthreads per tile.
// ---------------------------------------------------------------------------
__global__ __launch_bounds__(256, 3) void k_attn(const unsigned short* __restrict__ Q,
                                                 const unsigned short* __restrict__ Kf,
                                                 const unsigned short* __restrict__ Vf,
                                                 unsigned short* __restrict__ O) {
  __shared__ unsigned short ldsK[2][4096];
  __shared__ unsigned short ldsV[2][4096];

  int tid = threadIdx.x;
  int lane = tid & 63, wave = tid >> 6;
  int r16 = lane & 15, g = lane >> 4;

  // XCD-aware remap (bijective on 0..767)
  int bid = blockIdx.x;
  int gid = (bid & 7) * 96 + (bid >> 3);
  int h = gid >> 6;
  int qbase = (gid & 63) * 64 + wave * 16;

  const unsigned short* KfH = Kf + (size_t)h * (64 * 4096);
  const unsigned short* VfH = Vf + (size_t)h * (64 * 4096);

  // Q fragments (B-operand): lane holds Q[qbase+r16][8g..8g+7]
  const unsigned short* qptr = Q + ((size_t)h * S_LEN + qbase + r16) * HDIM + g * 8;
  bf16x8 qf0 = *reinterpret_cast<const bf16x8*>(qptr);
  bf16x8 qf1 = *reinterpret_cast<const bf16x8*>(qptr + 32);

  f32x4 oacc[4] = {};
  float mrow = -1e30f;  // running row max (exp2 domain), row-uniform
  float lacc = 0.f;     // this lane's partial l (its 16 keys/tile), current scale

  int c0 = wave, c1 = wave + 4;  // this wave's two 1KB chunks per buffer

#define STAGE(BUF, T)                                                        \
  do {                                                                       \
    const unsigned short* kg_ = KfH + (size_t)(T) * 4096;                    \
    const unsigned short* vg_ = VfH + (size_t)(T) * 4096;                    \
    gload_lds16(kg_ + c0 * 512 + lane * 8, &ldsK[BUF][c0 * 512]);            \
    gload_lds16(kg_ + c1 * 512 + lane * 8, &ldsK[BUF][c1 * 512]);            \
    gload_lds16(vg_ + c0 * 512 + lane * 8, &ldsV[BUF][c0 * 512]);            \
    gload_lds16(vg_ + c1 * 512 + lane * 8, &ldsV[BUF][c1 * 512]);            \
  } while (0)

  STAGE(0, 0);
  for (int t = 0; t < 64; ++t) {
    int cur = t & 1;
    __syncthreads();  // buf[cur] staged (own-vmcnt drained here); prev reads done

    // ---- fragments from LDS (lane-contiguous b128, conflict-free)
    bf16x8 kfr[8], vfr[8];
#pragma unroll
    for (int f = 0; f < 8; ++f) {
      kfr[f] = *reinterpret_cast<const bf16x8*>(&ldsK[cur][f * 512 + lane * 8]);
      vfr[f] = *reinterpret_cast<const bf16x8*>(&ldsV[cur][f * 512 + lane * 8]);
    }

    // ---- prefetch next tile into buf[cur^1]; drains at NEXT barrier (covered
    //      by compute below). Target buffer's last reads finished pre-barrier.
    if (t < 63) STAGE(cur ^ 1, t + 1);

    // ---- QK^T (swapped): s[j] = P_raw[q=r16][keys of frag j], exp2 domain
    f32x4 s[4];
#pragma unroll
    for (int j = 0; j < 4; ++j) {
      f32x4 z = {};
      z = __builtin_amdgcn_mfma_f32_16x16x32_bf16(kfr[2 * j], qf0, z, 0, 0, 0);
      s[j] = __builtin_amdgcn_mfma_f32_16x16x32_bf16(kfr[2 * j + 1], qf1, z, 0, 0, 0);
    }

    // ---- defer-max: row pmax (2 shuffles); rescale only if growth > 8
    float pmax = fmaxf(fmaxf(fmaxf(s[0][0], s[0][1]), fmaxf(s[0][2], s[0][3])),
                       fmaxf(fmaxf(s[1][0], s[1][1]), fmaxf(s[1][2], s[1][3])));
    float pm2 = fmaxf(fmaxf(fmaxf(s[2][0], s[2][1]), fmaxf(s[2][2], s[2][3])),
                      fmaxf(fmaxf(s[3][0], s[3][1]), fmaxf(s[3][2], s[3][3])));
    pmax = fmaxf(pmax, pm2);
    pmax = fmaxf(pmax, __shfl_xor(pmax, 16));
    pmax = fmaxf(pmax, __shfl_xor(pmax, 32));
    if (__any(pmax > mrow + 8.f)) {   // wave-uniform, branch skipped when cold
      float mnew = fmaxf(mrow, pmax);
      float al = exp2f(mrow - mnew);  // 0 on first tile (mrow=-1e30)
      lacc *= al;
      float a0 = __shfl(al, 20 * g + 0), a1 = __shfl(al, 20 * g + 1);
      float a2 = __shfl(al, 20 * g + 2), a3 = __shfl(al, 20 * g + 3);
#pragma unroll
      for (int j = 0; j < 4; ++j) {
        oacc[j][0] *= a0; oacc[j][1] *= a1;
        oacc[j][2] *= a2; oacc[j][3] *= a3;
      }
      mrow = mnew;
    }

    // ---- p = exp2(s - mrow) <= 2^8; per-lane partial l
    float p[4][4];
#pragma unroll
    for (int j = 0; j < 4; ++j)
#pragma unroll
      for (int i = 0; i < 4; ++i) {
        float e = exp2f(s[j][i] - mrow);
        p[j][i] = e;
        lacc += e;
      }

    // ---- lane-local P -> bf16 A-frags (native casts -> v_cvt_pk_bf16_f32)
    bf16x8 pa0, pa1;
#pragma unroll
    for (int e = 0; e < 8; ++e) {
      pa0[e] = (__bf16)p[2 * (e >> 2)][e & 3];
      pa1[e] = (__bf16)p[1 + 2 * (e >> 2)][e & 3];
    }

    // ---- PV
#pragma unroll
    for (int j = 0; j < 4; ++j) {
      oacc[j] = __builtin_amdgcn_mfma_f32_16x16x32_bf16(pa0, vfr[2 * j], oacc[j], 0, 0, 0);
      oacc[j] = __builtin_amdgcn_mfma_f32_16x16x32_bf16(pa1, vfr[2 * j + 1], oacc[j], 0, 0, 0);
    }
  }
#undef STAGE

  // ---- l reduction (once): lane partials -> row sum for q=r16
  float ls = lacc;
  ls += __shfl_xor(ls, 16);
  ls += __shfl_xor(ls, 32);

  // ---- epilogue: O[s][h*64+d] bf16, rows q = 4g+i need 1/l from lane 4g+i
#pragma unroll
  for (int i = 0; i < 4; ++i) {
    float linv = 1.0f / __shfl(ls, 20 * g + i);
    int srow = qbase + 4 * g + i;
#pragma unroll
    for (int j = 0; j < 4; ++j) {
      int col = h * HDIM + j * 16 + r16;
      O[(size_t)srow * DMODEL + col] = f2bf(oacc[j][i] * linv);
    }
  }
}

// ---------------------------------------------------------------------------
extern "C" void kernel_launch(void* const* d_in, const int* in_sizes, int n_in,
                              void* d_out, int out_size, void* d_ws, size_t ws_size,
                              hipStream_t stream) {
  const float* x = (const float*)d_in[0];       // [4096][768]
  const float* w_qkv = (const float*)d_in[1];   // [768][2304]
  const float* b_qkv = (const float*)d_in[2];   // [2304]
  const float* w_proj = (const float*)d_in[3];  // [768][768]
  const float* b_proj = (const float*)d_in[4];  // [768]
  float* out = (float*)d_out;                   // [4096][768]

  unsigned short* ws16 = (unsigned short*)d_ws;
  unsigned short* xb = ws16;                                   // 4096*768
  unsigned short* wqkvT = xb + (size_t)S_LEN * DMODEL;         // 2304*768
  unsigned short* wprojT = wqkvT + (size_t)DQKV * DMODEL;      // 768*768
  unsigned short* Qb = wprojT + (size_t)DMODEL * DMODEL;       // 12*4096*64
  unsigned short* Kf = Qb + (size_t)NHEAD * S_LEN * HDIM;
  unsigned short* Vf = Kf + (size_t)NHEAD * S_LEN * HDIM;
  unsigned short* Ob = xb;  // alias: x dead after QKV GEMM

  // 1) convert x
  k_convert<<<(S_LEN * DMODEL) / (256 * 8), 256, 0, stream>>>(x, xb, S_LEN * DMODEL);
  // 2) transpose-convert weights to [N][K] bf16
  k_transpose<<<dim3(DQKV / 64, DMODEL / 64), 256, 0, stream>>>(w_qkv, wqkvT, DMODEL, DQKV);
  k_transpose<<<dim3(DMODEL / 64, DMODEL / 64), 256, 0, stream>>>(w_proj, wprojT, DMODEL, DMODEL);
  // 3) QKV GEMM + fragment-linear scatter
  k_gemm<0><<<dim3(DQKV / 128, S_LEN / 128), 256, 0, stream>>>(xb, wqkvT, b_qkv, Qb, Kf, Vf, nullptr);
  // 4) attention (1D grid, XCD-remapped in-kernel)
  k_attn<<<768, 256, 0, stream>>>(Qb, Kf, Vf, Ob);
  // 5) output projection
  k_gemm<1><<<dim3(DMODEL / 128, S_LEN / 128), 256, 0, stream>>>(Ob, wprojT, b_proj, nullptr, nullptr, nullptr, out);
}

// Round 7
// 135.580 us; speedup vs baseline: 3.0908x; 1.1871x over previous
//
#include <hip/hip_runtime.h>

// Problem constants
#define S_LEN 4096
#define DMODEL 768
#define NHEAD 12
#define HDIM 64
#define DQKV 2304

typedef __attribute__((ext_vector_type(8))) __bf16 bf16x8;
typedef __attribute__((ext_vector_type(4))) float f32x4;
typedef __attribute__((ext_vector_type(8))) unsigned short ushort8;

#define LOG2E 1.4426950408889634f

#if __has_builtin(__builtin_amdgcn_exp2f)
#define EXP2(x) __builtin_amdgcn_exp2f(x)
#else
#define EXP2(x) exp2f(x)
#endif

static __device__ __forceinline__ unsigned short f2bf(float f) {
  unsigned int u = __float_as_uint(f);
  u += 0x7FFFu + ((u >> 16) & 1u);  // round-to-nearest-even
  return (unsigned short)(u >> 16);
}

// async global -> LDS, 16B per lane. Dest must be wave-uniform; HW writes
// lptr + lane*16. Global src is per-lane (contiguous here -> coalesced).
static __device__ __forceinline__ void gload_lds16(const unsigned short* g, unsigned short* l) {
  __builtin_amdgcn_global_load_lds(
      (const __attribute__((address_space(1))) unsigned int*)g,
      (__attribute__((address_space(3))) unsigned int*)l, 16, 0, 0);
}

// ---------------------------------------------------------------------------
// fp32 -> bf16 elementwise convert (n must be multiple of 8)
// ---------------------------------------------------------------------------
__global__ __launch_bounds__(256) void k_convert(const float* __restrict__ in,
                                                 unsigned short* __restrict__ out,
                                                 int n) {
  int i = (blockIdx.x * 256 + threadIdx.x) * 8;
  if (i >= n) return;
  const float4* p = reinterpret_cast<const float4*>(in + i);
  float4 a = p[0], b = p[1];
  ushort8 r;
  r[0] = f2bf(a.x); r[1] = f2bf(a.y); r[2] = f2bf(a.z); r[3] = f2bf(a.w);
  r[4] = f2bf(b.x); r[5] = f2bf(b.y); r[6] = f2bf(b.z); r[7] = f2bf(b.w);
  *reinterpret_cast<ushort8*>(out + i) = r;
}

// ---------------------------------------------------------------------------
// [K][N] fp32  ->  [N][K] bf16 transpose-convert, 64x64 tiles
// ---------------------------------------------------------------------------
__global__ __launch_bounds__(256) void k_transpose(const float* __restrict__ in,
                                                   unsigned short* __restrict__ out,
                                                   int Kdim, int Ndim) {
  __shared__ unsigned short t[64 * 65];
  int k0 = blockIdx.y * 64, n0 = blockIdx.x * 64;
  int tid = threadIdx.x;
#pragma unroll
  for (int p = 0; p < 4; ++p) {
    int r = p * 16 + (tid >> 4);   // k offset in tile
    int c = (tid & 15) * 4;        // n offset in tile
    float4 v = *reinterpret_cast<const float4*>(in + (size_t)(k0 + r) * Ndim + n0 + c);
    t[(c + 0) * 65 + r] = f2bf(v.x);
    t[(c + 1) * 65 + r] = f2bf(v.y);
    t[(c + 2) * 65 + r] = f2bf(v.z);
    t[(c + 3) * 65 + r] = f2bf(v.w);
  }
  __syncthreads();
#pragma unroll
  for (int p = 0; p < 2; ++p) {
    int task = p * 256 + tid;
    int rr = task >> 3;        // n offset
    int cc = (task & 7) * 8;   // k offset
    ushort8 r;
#pragma unroll
    for (int j = 0; j < 8; ++j) r[j] = t[rr * 65 + cc + j];
    *reinterpret_cast<ushort8*>(out + (size_t)(n0 + rr) * Kdim + k0 + cc) = r;
  }
}

// ---------------------------------------------------------------------------
// bf16 MFMA GEMM: C[M=4096][N] = A[M][768] * Bt[N][768]^T
// 128x128 block tile, BK=32, 4 waves, 4x4 16x16x32 frags per wave.
// global_load_lds staging (16B, linear LDS), double-buffered, ONE barrier
// per K-step (stage-after-read order; stage drains at next barrier).
// MODE 0: QKV epilogue (Q scaled, K/V fragment-linear scatter)
// MODE 1: proj epilogue (fp32 out + bias)
// ---------------------------------------------------------------------------
template <int MODE>
__global__ __launch_bounds__(256) void k_gemm(const unsigned short* __restrict__ A,
                                              const unsigned short* __restrict__ Bt,
                                              const float* __restrict__ bias,
                                              unsigned short* __restrict__ Qb,
                                              unsigned short* __restrict__ Kf,
                                              unsigned short* __restrict__ Vf,
                                              float* __restrict__ outf) {
  __shared__ unsigned short As[2][128 * 32];
  __shared__ unsigned short Bs[2][128 * 32];

  int tid = threadIdx.x;
  int lane = tid & 63, wave = tid >> 6;
  int wr = wave >> 1, wc = wave & 1;         // wave -> 64x64 subtile
  int m0 = blockIdx.y * 128, n0 = blockIdx.x * 128;
  int r16 = lane & 15, g = lane >> 4;

  // staging: 8 chunks of 1KB per tile (16 rows x 64B); wave stages 2 of A + 2 of B
  int ca0 = wave * 2, ca1 = wave * 2 + 1;
  int srow = lane >> 2, scol = (lane & 3) * 8;  // within-chunk source (row, col elems)

  f32x4 acc[4][4] = {};

#define GSTAGE(BUF, K0)                                                                 \
  do {                                                                                  \
    gload_lds16(A + (size_t)(m0 + ca0 * 16 + srow) * DMODEL + (K0) + scol,              \
                &As[BUF][ca0 * 512]);                                                   \
    gload_lds16(A + (size_t)(m0 + ca1 * 16 + srow) * DMODEL + (K0) + scol,              \
                &As[BUF][ca1 * 512]);                                                   \
    gload_lds16(Bt + (size_t)(n0 + ca0 * 16 + srow) * DMODEL + (K0) + scol,             \
                &Bs[BUF][ca0 * 512]);                                                   \
    gload_lds16(Bt + (size_t)(n0 + ca1 * 16 + srow) * DMODEL + (K0) + scol,             \
                &Bs[BUF][ca1 * 512]);                                                   \
  } while (0)

  GSTAGE(0, 0);
  for (int kt = 0; kt < DMODEL / 32; ++kt) {
    int cur = kt & 1;
    __syncthreads();  // drains prev stage (own vmcnt) + all waves' reads of buf[cur^1]

    bf16x8 af[4], bfr[4];
#pragma unroll
    for (int m = 0; m < 4; ++m)
      af[m] = *reinterpret_cast<const bf16x8*>(&As[cur][(wr * 64 + m * 16 + r16) * 32 + g * 8]);
#pragma unroll
    for (int n = 0; n < 4; ++n)
      bfr[n] = *reinterpret_cast<const bf16x8*>(&Bs[cur][(wc * 64 + n * 16 + r16) * 32 + g * 8]);

    if (kt < DMODEL / 32 - 1) GSTAGE(cur ^ 1, (kt + 1) * 32);

#pragma unroll
    for (int m = 0; m < 4; ++m)
#pragma unroll
      for (int n = 0; n < 4; ++n)
        acc[m][n] = __builtin_amdgcn_mfma_f32_16x16x32_bf16(af[m], bfr[n], acc[m][n], 0, 0, 0);
  }
#undef GSTAGE

  // Epilogue. C/D frag layout: col = lane&15, row = 4*(lane>>4) + reg  [HW-verified]
#pragma unroll
  for (int m = 0; m < 4; ++m) {
    int grow0 = m0 + wr * 64 + m * 16 + 4 * g;  // s index base (4 consecutive)
#pragma unroll
    for (int n = 0; n < 4; ++n) {
      int gcol = n0 + wc * 64 + n * 16 + r16;
      float bv = bias[gcol];
      if (MODE == 0) {
        int sect = gcol / DMODEL;        // uniform per block (768 = 6*128)
        int rem = gcol - sect * DMODEL;
        int h = rem >> 6, hd = rem & 63;
        if (sect == 2) {
          // V fragment-linear: elem (h,tile,f=j*2+kk,lane2=g2*16+r16v,e)
          //   = V[d = j*16+r16v][s = tile*64 + kk*32 + g2*8 + e]
          int j = hd >> 4, r16v = hd & 15;
          int tile = grow0 >> 6, kk = (grow0 >> 5) & 1, g2 = (grow0 >> 3) & 3, e0 = grow0 & 7;
          size_t base = (((size_t)h * 64 + tile) * 8 + (j * 2 + kk)) * 512 +
                        (size_t)(g2 * 16 + r16v) * 8 + e0;
          ushort4 pk;
          pk.x = f2bf(acc[m][n][0] + bv);
          pk.y = f2bf(acc[m][n][1] + bv);
          pk.z = f2bf(acc[m][n][2] + bv);
          pk.w = f2bf(acc[m][n][3] + bv);
          *reinterpret_cast<ushort4*>(Vf + base) = pk;
        } else if (sect == 0) {
          // Q: [h][s][d], folded 1/sqrt(64)*log2e (attention runs in exp2 domain)
#pragma unroll
          for (int i = 0; i < 4; ++i)
            Qb[((size_t)h * S_LEN + grow0 + i) * HDIM + hd] =
                f2bf((acc[m][n][i] + bv) * (0.125f * LOG2E));
        } else {
          // K fragment-linear: elem (h,tile,f=j*2+kk,lane2=g2*16+r16l,e)
          //   = K[s = tile*64 + krow][d = kk*32 + g2*8 + e]
          // krow = 32*(j&1) + 4*(j>>1) + 8*(r16l>>2) + (r16l&3)
          int kk = hd >> 5, g2 = (hd >> 3) & 3, e = hd & 7;
#pragma unroll
          for (int i = 0; i < 4; ++i) {
            int s = grow0 + i;
            int tile = s >> 6, r = s & 63;
            int j = (((r >> 2) & 1) << 1) | (r >> 5);
            int r16l = (r & 3) | (((r >> 3) & 3) << 2);
            size_t idx = (((size_t)h * 64 + tile) * 8 + (j * 2 + kk)) * 512 +
                         (size_t)(g2 * 16 + r16l) * 8 + e;
            Kf[idx] = f2bf(acc[m][n][i] + bv);
          }
        }
      } else {
#pragma unroll
        for (int i = 0; i < 4; ++i)
          outf[(size_t)(grow0 + i) * DMODEL + gcol] = acc[m][n][i] + bv;
      }
    }
  }
}

// ---------------------------------------------------------------------------
// Flash attention, LDS-staged fragment-linear K/V, defer-max online softmax.
// VALU-diet version of R6 (same proven numerics):
//  - QK^T accumulator seeded with -mrow (zinit) -> no per-tile subs
//  - l computed by ones-MFMA from the SAME bf16 p-hat as PV -> no per-tile
//    adds, no epilogue reduce, denominator consistent with numerator
//  - tile 0 peeled to establish mrow exactly (R5 showed mrow=0 fails)
//  - explicit pair-unrolled loop: compile-time buffer parity
// ---------------------------------------------------------------------------
__global__ __launch_bounds__(256, 3) void k_attn(const unsigned short* __restrict__ Q,
                                                 const unsigned short* __restrict__ Kf,
                                                 const unsigned short* __restrict__ Vf,
                                                 unsigned short* __restrict__ O) {
  __shared__ unsigned short ldsK[2][4096];
  __shared__ unsigned short ldsV[2][4096];

  int tid = threadIdx.x;
  int lane = tid & 63, wave = tid >> 6;
  int r16 = lane & 15, g = lane >> 4;

  // XCD-aware remap (bijective on 0..767)
  int bid = blockIdx.x;
  int gid = (bid & 7) * 96 + (bid >> 3);
  int h = gid >> 6;
  int qbase = (gid & 63) * 64 + wave * 16;

  const unsigned short* KfH = Kf + (size_t)h * (64 * 4096);
  const unsigned short* VfH = Vf + (size_t)h * (64 * 4096);

  // Q fragments (B-operand): lane holds Q[qbase+r16][8g..8g+7]
  const unsigned short* qptr = Q + ((size_t)h * S_LEN + qbase + r16) * HDIM + g * 8;
  bf16x8 qf0 = *reinterpret_cast<const bf16x8*>(qptr);
  bf16x8 qf1 = *reinterpret_cast<const bf16x8*>(qptr + 32);

  f32x4 oacc[4] = {};
  f32x4 lsum = {};            // C layout row=q=4g+i -> epilogue needs no shuffle
  f32x4 zinit = {};           // splat(-mrow); 0 for peeled tile 0
  float mrow = 0.f;           // running row max (exp2 domain), per-lane q=r16
  bf16x8 bones;
#pragma unroll
  for (int e = 0; e < 8; ++e) bones[e] = (__bf16)1.0f;

  int c0 = wave, c1 = wave + 4;  // this wave's two 1KB chunks per buffer

#define STAGE(BUF, T)                                                        \
  do {                                                                       \
    const unsigned short* kg_ = KfH + (size_t)(T) * 4096;                    \
    const unsigned short* vg_ = VfH + (size_t)(T) * 4096;                    \
    gload_lds16(kg_ + c0 * 512 + lane * 8, &ldsK[BUF][c0 * 512]);            \
    gload_lds16(kg_ + c1 * 512 + lane * 8, &ldsK[BUF][c1 * 512]);            \
    gload_lds16(vg_ + c0 * 512 + lane * 8, &ldsV[BUF][c0 * 512]);            \
    gload_lds16(vg_ + c1 * 512 + lane * 8, &ldsV[BUF][c1 * 512]);            \
  } while (0)

#define TILE_COMPUTE(KFR, VFR, FIRST)                                                   \
  do {                                                                                  \
    f32x4 s_[4];                                                                        \
    _Pragma("unroll") for (int j_ = 0; j_ < 4; ++j_) {                                  \
      f32x4 z_ = zinit;                                                                 \
      z_ = __builtin_amdgcn_mfma_f32_16x16x32_bf16(KFR[2 * j_], qf0, z_, 0, 0, 0);      \
      s_[j_] = __builtin_amdgcn_mfma_f32_16x16x32_bf16(KFR[2 * j_ + 1], qf1, z_, 0, 0, 0); \
    }                                                                                   \
    /* row max: max3-friendly triples (8 ops) + 2 shuffles */                           \
    float x1_ = fmaxf(fmaxf(s_[0][0], s_[0][1]), s_[0][2]);                             \
    float x2_ = fmaxf(fmaxf(s_[0][3], s_[1][0]), s_[1][1]);                             \
    float x3_ = fmaxf(fmaxf(s_[1][2], s_[1][3]), s_[2][0]);                             \
    float x4_ = fmaxf(fmaxf(s_[2][1], s_[2][2]), s_[2][3]);                             \
    float x5_ = fmaxf(fmaxf(s_[3][0], s_[3][1]), s_[3][2]);                             \
    float pm_ = fmaxf(fmaxf(fmaxf(x1_, x2_), fmaxf(x3_, x4_)), fmaxf(x5_, s_[3][3]));   \
    pm_ = fmaxf(pm_, __shfl_xor(pm_, 16));                                              \
    pm_ = fmaxf(pm_, __shfl_xor(pm_, 32));                                              \
    if (FIRST) {                                                                        \
      /* establish mrow exactly on tile 0 (p <= 1 afterwards) */                        \
      _Pragma("unroll") for (int j_ = 0; j_ < 4; ++j_)                                  \
        _Pragma("unroll") for (int i_ = 0; i_ < 4; ++i_) s_[j_][i_] -= pm_;             \
      mrow = pm_;                                                                       \
      zinit[0] = -mrow; zinit[1] = -mrow; zinit[2] = -mrow; zinit[3] = -mrow;           \
    } else if (__any(pm_ > 8.f)) { /* defer-max THR=8, wave-uniform, rare */            \
      float dl_ = fmaxf(pm_, 0.f);                                                      \
      float al_ = EXP2(-dl_);                                                           \
      float a0_ = __shfl(al_, 20 * g + 0), a1_ = __shfl(al_, 20 * g + 1);               \
      float a2_ = __shfl(al_, 20 * g + 2), a3_ = __shfl(al_, 20 * g + 3);               \
      lsum[0] *= a0_; lsum[1] *= a1_; lsum[2] *= a2_; lsum[3] *= a3_;                   \
      _Pragma("unroll") for (int j_ = 0; j_ < 4; ++j_) {                                \
        oacc[j_][0] *= a0_; oacc[j_][1] *= a1_;                                         \
        oacc[j_][2] *= a2_; oacc[j_][3] *= a3_;                                         \
      }                                                                                 \
      _Pragma("unroll") for (int j_ = 0; j_ < 4; ++j_)                                  \
        _Pragma("unroll") for (int i_ = 0; i_ < 4; ++i_) s_[j_][i_] -= dl_;             \
      mrow += dl_;                                                                      \
      zinit[0] = -mrow; zinit[1] = -mrow; zinit[2] = -mrow; zinit[3] = -mrow;           \
    }                                                                                   \
    float p_[4][4];                                                                     \
    _Pragma("unroll") for (int j_ = 0; j_ < 4; ++j_)                                    \
      _Pragma("unroll") for (int i_ = 0; i_ < 4; ++i_)                                  \
        p_[j_][i_] = EXP2(s_[j_][i_]);                                                  \
    /* lane-local P -> bf16 A-frags (v_cvt_pk_bf16_f32 pairs) */                        \
    bf16x8 pa0_, pa1_;                                                                  \
    _Pragma("unroll") for (int e_ = 0; e_ < 8; ++e_) {                                  \
      pa0_[e_] = (__bf16)p_[2 * (e_ >> 2)][e_ & 3];                                     \
      pa1_[e_] = (__bf16)p_[1 + 2 * (e_ >> 2)][e_ & 3];                                 \
    }                                                                                   \
    /* l from the SAME bf16 p-hat as PV (consistent denominator) */                     \
    lsum = __builtin_amdgcn_mfma_f32_16x16x32_bf16(pa0_, bones, lsum, 0, 0, 0);         \
    lsum = __builtin_amdgcn_mfma_f32_16x16x32_bf16(pa1_, bones, lsum, 0, 0, 0);         \
    _Pragma("unroll") for (int j_ = 0; j_ < 4; ++j_) {                                  \
      oacc[j_] = __builtin_amdgcn_mfma_f32_16x16x32_bf16(pa0_, VFR[2 * j_], oacc[j_], 0, 0, 0); \
      oacc[j_] = __builtin_amdgcn_mfma_f32_16x16x32_bf16(pa1_, VFR[2 * j_ + 1], oacc[j_], 0, 0, 0); \
    }                                                                                   \
  } while (0)

#define BODY(T, CUR, DO_STAGE, FIRSTF)                                                  \
  do {                                                                                  \
    __syncthreads(); /* buf[CUR] staged (own vmcnt drained); prev reads done */         \
    bf16x8 kfr_[8], vfr_[8];                                                            \
    _Pragma("unroll") for (int f_ = 0; f_ < 8; ++f_) {                                  \
      kfr_[f_] = *reinterpret_cast<const bf16x8*>(&ldsK[CUR][f_ * 512 + lane * 8]);     \
      vfr_[f_] = *reinterpret_cast<const bf16x8*>(&ldsV[CUR][f_ * 512 + lane * 8]);     \
    }                                                                                   \
    if (DO_STAGE) STAGE((CUR) ^ 1, (T) + 1);                                            \
    TILE_COMPUTE(kfr_, vfr_, FIRSTF);                                                   \
  } while (0)

  STAGE(0, 0);
  BODY(0, 0, true, true);
  for (int pr = 0; pr < 31; ++pr) {
    BODY(2 * pr + 1, 1, true, false);
    BODY(2 * pr + 2, 0, true, false);
  }
  BODY(63, 1, false, false);
#undef BODY
#undef TILE_COMPUTE
#undef STAGE

  // ---- epilogue: O[s][h*64+d] bf16; lsum[i] is row q=4g+i's l (no shuffle)
#pragma unroll
  for (int i = 0; i < 4; ++i) {
    float linv = 1.0f / lsum[i];
    int srow = qbase + 4 * g + i;
#pragma unroll
    for (int j = 0; j < 4; ++j) {
      int col = h * HDIM + j * 16 + r16;
      O[(size_t)srow * DMODEL + col] = f2bf(oacc[j][i] * linv);
    }
  }
}

// ---------------------------------------------------------------------------
extern "C" void kernel_launch(void* const* d_in, const int* in_sizes, int n_in,
                              void* d_out, int out_size, void* d_ws, size_t ws_size,
                              hipStream_t stream) {
  const float* x = (const float*)d_in[0];       // [4096][768]
  const float* w_qkv = (const float*)d_in[1];   // [768][2304]
  const float* b_qkv = (const float*)d_in[2];   // [2304]
  const float* w_proj = (const float*)d_in[3];  // [768][768]
  const float* b_proj = (const float*)d_in[4];  // [768]
  float* out = (float*)d_out;                   // [4096][768]

  unsigned short* ws16 = (unsigned short*)d_ws;
  unsigned short* xb = ws16;                                   // 4096*768
  unsigned short* wqkvT = xb + (size_t)S_LEN * DMODEL;         // 2304*768
  unsigned short* wprojT = wqkvT + (size_t)DQKV * DMODEL;      // 768*768
  unsigned short* Qb = wprojT + (size_t)DMODEL * DMODEL;       // 12*4096*64
  unsigned short* Kf = Qb + (size_t)NHEAD * S_LEN * HDIM;
  unsigned short* Vf = Kf + (size_t)NHEAD * S_LEN * HDIM;
  unsigned short* Ob = xb;  // alias: x dead after QKV GEMM

  // 1) convert x
  k_convert<<<(S_LEN * DMODEL) / (256 * 8), 256, 0, stream>>>(x, xb, S_LEN * DMODEL);
  // 2) transpose-convert weights to [N][K] bf16
  k_transpose<<<dim3(DQKV / 64, DMODEL / 64), 256, 0, stream>>>(w_qkv, wqkvT, DMODEL, DQKV);
  k_transpose<<<dim3(DMODEL / 64, DMODEL / 64), 256, 0, stream>>>(w_proj, wprojT, DMODEL, DMODEL);
  // 3) QKV GEMM + fragment-linear scatter
  k_gemm<0><<<dim3(DQKV / 128, S_LEN / 128), 256, 0, stream>>>(xb, wqkvT, b_qkv, Qb, Kf, Vf, nullptr);
  // 4) attention (1D grid, XCD-remapped in-kernel)
  k_attn<<<768, 256, 0, stream>>>(Qb, Kf, Vf, Ob);
  // 5) output projection
  k_gemm<1><<<dim3(DMODEL / 128, S_LEN / 128), 256, 0, stream>>>(Ob, wprojT, b_proj, nullptr, nullptr, nullptr, out);
}